// Round 10
// baseline (372.985 us; speedup 1.0000x reference)
//
#include <hip/hip_runtime.h>
#include <math.h>

// ---------------------------------------------------------------------------
// Round 10: conv->K->V fused kernel (X4 never touches global; K/V have zero
//           A-gloads) + a3p stored bf16. Rest = R9.
// Shapes (idx==10): bs=16, c=256, h=w=40, S=1600, T=25600, heads=8, hd=32
// ws float-offsets:
//   POS 0 | WBF 409600(bf16 weights) | KV 868352 | KS 1130496 | KVP 1138688
//   KSP 2449408 | X3bf 2490368 | (X4 slot unused) | QBbf 9043968
//   KBbf 12320768 | VBbf 15597568 | OUT1bf 18874368 | A4T/FFHbf 22151168
//   A3P bf16 [b][c][40][40] at 9043968 (reuses QB, dead by lin2)
// ---------------------------------------------------------------------------

typedef __attribute__((ext_vector_type(8))) short bf16x8;
typedef __attribute__((ext_vector_type(8))) unsigned short us8;
typedef __attribute__((ext_vector_type(4))) unsigned short us4h;
typedef __attribute__((ext_vector_type(4))) float f32x4;

__device__ __forceinline__ unsigned short f2bf(float f) {
  unsigned int u = __float_as_uint(f);
  u += 0x7fff + ((u >> 16) & 1);  // RNE
  return (unsigned short)(u >> 16);
}
__device__ __forceinline__ float bf2f(unsigned short u) {
  return __uint_as_float(((unsigned int)u) << 16);
}

// async global->LDS, 16B per lane; LDS dest = wave-uniform base + lane*16
__device__ __forceinline__ void gload16(const void* g, void* l) {
  __builtin_amdgcn_global_load_lds(
      (const __attribute__((address_space(1))) void*)g,
      (__attribute__((address_space(3))) void*)l, 16, 0, 0);
}

// --- prep: [0,448) weights->bf16 ; [448,2048) pos ; [2048,5248) a4 transpose ---
__global__ __launch_bounds__(256) void prep_kernel(
    const float* __restrict__ cw, const float* __restrict__ qw,
    const float* __restrict__ kw, const float* __restrict__ vw,
    const float* __restrict__ ow, const float* __restrict__ l1w,
    const float* __restrict__ l2w, unsigned short* __restrict__ wbf,
    float* __restrict__ pos,
    const float* __restrict__ a4, unsigned short* __restrict__ a4t) {
  __shared__ float buf[64][65];
  if (blockIdx.x < 448) {
    int gid = blockIdx.x * 256 + threadIdx.x;
    size_t e0 = (size_t)gid * 8;
    const float* src; size_t off;
    if (e0 < 131072)      { src = cw;  off = e0; }
    else if (e0 < 196608) { src = qw;  off = e0 - 131072; }
    else if (e0 < 262144) { src = kw;  off = e0 - 196608; }
    else if (e0 < 327680) { src = vw;  off = e0 - 262144; }
    else if (e0 < 393216) { src = ow;  off = e0 - 327680; }
    else if (e0 < 655360) { src = l1w; off = e0 - 393216; }
    else                  { src = l2w; off = e0 - 655360; }
    float4 v0 = *(const float4*)(src + off);
    float4 v1 = *(const float4*)(src + off + 4);
    us8 r;
    r[0] = f2bf(v0.x); r[1] = f2bf(v0.y); r[2] = f2bf(v0.z); r[3] = f2bf(v0.w);
    r[4] = f2bf(v1.x); r[5] = f2bf(v1.y); r[6] = f2bf(v1.z); r[7] = f2bf(v1.w);
    *(us8*)(wbf + e0) = r;
  } else if (blockIdx.x < 2048) {
    int s = blockIdx.x - 448, c = threadIdx.x;
    int y = s / 40, x = s - y * 40;
    int quad = c >> 6, i = c & 63;
    float omega = expf(-(float)i * (9.2103403719761836f / 64.0f));
    float coord = (quad < 2) ? (float)y : (float)x;
    float a = coord * omega;
    pos[s * 256 + c] = (quad & 1) ? cosf(a) : sinf(a);
  } else {
    int id = blockIdx.x - 2048;          // 0..3199
    int b = id / 200;
    int r = id - b * 200;
    int s0 = (r % 25) * 64, k0 = (r / 25) * 64;
    const float* src = a4 + ((size_t)b * 512 + k0) * 1600 + s0;
#pragma unroll
    for (int p = 0; p < 4; ++p) {
      int idx = p * 256 + threadIdx.x;
      int kk = idx >> 4, s4 = (idx & 15) * 4;
      float4 v = *(const float4*)(src + (size_t)kk * 1600 + s4);
      buf[kk][s4 + 0] = v.x; buf[kk][s4 + 1] = v.y;
      buf[kk][s4 + 2] = v.z; buf[kk][s4 + 3] = v.w;
    }
    __syncthreads();
    unsigned short* dst = a4t + ((size_t)b * 1600 + s0) * 512 + k0;
#pragma unroll
    for (int p = 0; p < 4; ++p) {
      int idx = p * 256 + threadIdx.x;
      int ss = idx >> 4, kq = (idx & 15) * 4;
      us4h v;
      v[0] = f2bf(buf[kq + 0][ss]); v[1] = f2bf(buf[kq + 1][ss]);
      v[2] = f2bf(buf[kq + 2][ss]); v[3] = f2bf(buf[kq + 3][ss]);
      *(us4h*)(dst + (size_t)ss * 512 + kq) = v;
    }
  }
}

// a3 (b,c,80,80) -> X3bf[t][c] = avgpool2 + pos (bf16)
__global__ __launch_bounds__(640) void avgpool_kernel(
    const float* __restrict__ a3, const float* __restrict__ pos,
    unsigned short* __restrict__ X3) {
  __shared__ float buf2[256][44];
  int y = blockIdx.x, b = blockIdx.y;
  int tid = threadIdx.x;
  int x2 = tid % 20, cq = tid / 20;
#pragma unroll
  for (int it = 0; it < 8; ++it) {
    int c = cq + 32 * it;
    const float* p = a3 + (((size_t)(b * 256 + c) * 80 + 2 * y) * 80 + x2 * 4);
    float4 r0 = *(const float4*)p;
    float4 r1 = *(const float4*)(p + 80);
    buf2[c][2 * x2]     = 0.25f * ((r0.x + r0.y) + (r1.x + r1.y));
    buf2[c][2 * x2 + 1] = 0.25f * ((r0.z + r0.w) + (r1.z + r1.w));
  }
  __syncthreads();
  size_t t0 = (size_t)b * 1600 + y * 40;
  int sbase = y * 40;
#pragma unroll
  for (int it = 0; it < 4; ++it) {
    int idx = it * 640 + tid;
    int c = idx & 255, xq = idx >> 8;
    int x0 = xq * 4;
    float4 v = *(const float4*)&buf2[c][x0];
#pragma unroll
    for (int j = 0; j < 4; ++j) {
      float pv = pos[(size_t)(sbase + x0 + j) * 256 + c];
      float vv = (j == 0) ? v.x : (j == 1) ? v.y : (j == 2) ? v.z : v.w;
      X3[(t0 + x0 + j) * 256 + c] = f2bf(vv + pv);
    }
  }
}

// ---------------------------------------------------------------------------
// shared GEMM LDS (BK=64, two [rows][32] K-half subtiles, 64B rows)
// ---------------------------------------------------------------------------
struct __align__(16) SmemT {
  unsigned short Albs[2][64][32];
  unsigned short Wlds[2][256][32];
  float part[4][64][2];
};

template<int EPI>
__device__ __forceinline__ void gemm_body(
    SmemT& S,
    const unsigned short* __restrict__ A, const unsigned short* __restrict__ W,
    const float* __restrict__ bias, void* __restrict__ outp,
    const int K, const int ldN, int t0, int o0,
    const float* __restrict__ posb,
    const float* __restrict__ g1, const float* __restrict__ b1,
    const unsigned short* __restrict__ res) {
  int tid = threadIdx.x;
  int lane = tid & 63, w = tid >> 6;      // 8 waves
  int mw = w >> 2, nw = w & 3;
  int g = lane >> 4, cl = lane & 15;
  f32x4 acc[2][4] = {};

  int lrow = lane >> 2, lchk = lane & 3;
  const unsigned short* ag = A + (size_t)(t0 + (w >> 1) * 16 + lrow) * K
                               + (w & 1) * 32 + lchk * 8;
  unsigned short* al = &S.Albs[w & 1][(w >> 1) * 16][0];
  const unsigned short* wg[4];
  unsigned short* wl[4];
#pragma unroll
  for (int j = 0; j < 4; ++j) {
    int u = w * 4 + j;
    int kk = u & 1, rb = u >> 1;
    wg[j] = W + (size_t)(o0 + rb * 16 + lrow) * K + kk * 32 + lchk * 8;
    wl[j] = &S.Wlds[kk][rb * 16][0];
  }

  for (int k0 = 0; k0 < K; k0 += 64) {
    __syncthreads();
    gload16(ag + k0, al);
#pragma unroll
    for (int j = 0; j < 4; ++j) gload16(wg[j] + k0, wl[j]);
    __syncthreads();
#pragma unroll
    for (int kk = 0; kk < 2; ++kk) {
      bf16x8 af[2], bw[4];
#pragma unroll
      for (int ms = 0; ms < 2; ++ms)
        af[ms] = *(const bf16x8*)&S.Albs[kk][mw * 32 + ms * 16 + cl][g * 8];
#pragma unroll
      for (int ns = 0; ns < 4; ++ns)
        bw[ns] = *(const bf16x8*)&S.Wlds[kk][nw * 64 + ns * 16 + cl][g * 8];
#pragma unroll
      for (int ms = 0; ms < 2; ++ms)
#pragma unroll
        for (int ns = 0; ns < 4; ++ns)
          acc[ms][ns] = __builtin_amdgcn_mfma_f32_16x16x32_bf16(af[ms], bw[ns], acc[ms][ns], 0, 0, 0);
    }
  }

  float bv[4];
#pragma unroll
  for (int ns = 0; ns < 4; ++ns) bv[ns] = bias[o0 + nw * 64 + ns * 16 + cl];
  int sbase = t0 % 1600;  // 1600 % 64 == 0: block never crosses batch

  if constexpr (EPI == 2 || EPI == 3 || EPI == 5) {
#pragma unroll
    for (int ms = 0; ms < 2; ++ms) {
#pragma unroll
      for (int i = 0; i < 4; ++i) {
        float p = 0.f, q = 0.f;
#pragma unroll
        for (int ns = 0; ns < 4; ++ns) {
          float v = acc[ms][ns][i] + bv[ns];
          p += v; q += v * v;
        }
        p += __shfl_xor(p, 1); q += __shfl_xor(q, 1);
        p += __shfl_xor(p, 2); q += __shfl_xor(q, 2);
        p += __shfl_xor(p, 4); q += __shfl_xor(q, 4);
        p += __shfl_xor(p, 8); q += __shfl_xor(q, 8);
        if (cl == 0) {
          int rl = mw * 32 + ms * 16 + g * 4 + i;
          S.part[nw][rl][0] = p;
          S.part[nw][rl][1] = q;
        }
      }
    }
    __syncthreads();
  }

  if constexpr (EPI == 5) {
    // LN2 + residual, stored transposed BF16: out[b][col][s]
    unsigned short* ob2 = (unsigned short*)outp;
    int bb = t0 / 1600;
#pragma unroll
    for (int ms = 0; ms < 2; ++ms) {
      int rl0 = mw * 32 + ms * 16 + g * 4;
      float mean[4], inv[4];
#pragma unroll
      for (int i = 0; i < 4; ++i) {
        float sp = (S.part[0][rl0 + i][0] + S.part[1][rl0 + i][0]) +
                   (S.part[2][rl0 + i][0] + S.part[3][rl0 + i][0]);
        float sq = (S.part[0][rl0 + i][1] + S.part[1][rl0 + i][1]) +
                   (S.part[2][rl0 + i][1] + S.part[3][rl0 + i][1]);
        mean[i] = sp * (1.f / 256.f);
        float var = sq * (1.f / 256.f) - mean[i] * mean[i];
        inv[i] = rsqrtf(var + 1e-5f);
      }
#pragma unroll
      for (int ns = 0; ns < 4; ++ns) {
        int col = nw * 64 + ns * 16 + cl;
        float gg = g1[col], b2 = b1[col];
        us4h y;
#pragma unroll
        for (int i = 0; i < 4; ++i) {
          float v = acc[ms][ns][i] + bv[ns];
          float yy = (v - mean[i]) * inv[i] * gg + b2;
          yy += bf2f(res[(size_t)(t0 + rl0 + i) * 256 + col]);
          y[i] = f2bf(yy);
        }
        *(us4h*)(ob2 + ((size_t)(bb * 256 + col) * 1600) + sbase + rl0) = y;
      }
    }
    return;
  }

  unsigned short* ob = (unsigned short*)outp;
#pragma unroll
  for (int ms = 0; ms < 2; ++ms) {
#pragma unroll
    for (int i = 0; i < 4; ++i) {
      int rl = mw * 32 + ms * 16 + g * 4 + i;
      int t = t0 + rl;
      float mean = 0.f, inv = 0.f;
      if constexpr (EPI == 2 || EPI == 3) {
        float sp = (S.part[0][rl][0] + S.part[1][rl][0]) + (S.part[2][rl][0] + S.part[3][rl][0]);
        float sq = (S.part[0][rl][1] + S.part[1][rl][1]) + (S.part[2][rl][1] + S.part[3][rl][1]);
        mean = sp * (1.f / 256.f);
        float var = sq * (1.f / 256.f) - mean * mean;
        inv = rsqrtf(var + 1e-5f);
      }
#pragma unroll
      for (int ns = 0; ns < 4; ++ns) {
        int col = nw * 64 + ns * 16 + cl;
        float v = acc[ms][ns][i] + bv[ns];
        size_t oidx = (size_t)t * ldN + o0 + col;
        if constexpr (EPI == 0) {
          ob[oidx] = f2bf(v);
        } else if constexpr (EPI == 2) {
          float y = (v - mean) * inv * g1[col] + b1[col];
          ob[oidx] = f2bf(fmaxf(y, 0.f));
        } else if constexpr (EPI == 3) {
          float y = (v - mean) * inv * g1[col] + b1[col];
          y += bf2f(res[(size_t)t * 256 + col]) - posb[(size_t)(sbase + rl) * 256 + col];
          ob[oidx] = f2bf(y);
        } else if constexpr (EPI == 4) {
          float y = 0.5f * v * (1.f + erff(v * 0.7071067811865475f));
          ob[oidx] = f2bf(y);
        }
      }
    }
  }
}

template<int EPI>
__global__ __launch_bounds__(512) void fgemm(
    const unsigned short* __restrict__ A, const unsigned short* __restrict__ W,
    const float* __restrict__ bias, void* __restrict__ outp,
    const int K, const int ldN,
    const float* __restrict__ posb,
    const float* __restrict__ g1, const float* __restrict__ b1,
    const unsigned short* __restrict__ res) {
  __shared__ SmemT S;
  gemm_body<EPI>(S, A, W, bias, outp, K, ldN, blockIdx.x * 64, blockIdx.y * 256,
                 posb, g1, b1, res);
}

// ---------------------------------------------------------------------------
// convkv: conv(BN+pos) -> X4 tile kept in LDS -> K (LN+ReLU) -> V. One block
// owns 64 t-rows; K/V phases have zero A-gloads.
// ---------------------------------------------------------------------------
__global__ __launch_bounds__(512) void convkv_kernel(
    const unsigned short* __restrict__ a4tb, const unsigned short* __restrict__ w_conv,
    const unsigned short* __restrict__ w_k, const unsigned short* __restrict__ w_v,
    const float* __restrict__ conv_b, const float* __restrict__ k_b,
    const float* __restrict__ v_b,
    const float* __restrict__ bn_g, const float* __restrict__ bn_b,
    const float* __restrict__ posb,
    const float* __restrict__ k_g, const float* __restrict__ k_bt,
    unsigned short* __restrict__ Ko, unsigned short* __restrict__ Vo) {
  __shared__ SmemT S;
  __shared__ unsigned short X4L[4][2][64][32];   // 64 rows x 256 ch, chunked
  int tid = threadIdx.x;
  int lane = tid & 63, w = tid >> 6;
  int mw = w >> 2, nw = w & 3;
  int g = lane >> 4, cl = lane & 15;
  int lrow = lane >> 2, lchk = lane & 3;
  int t0 = blockIdx.x * 64;
  int sbase = t0 % 1600;
  f32x4 acc[2][4] = {};

  // ---- phase 1: conv (A = a4tb, K=512) ----
  {
    const unsigned short* ag = a4tb + (size_t)(t0 + (w >> 1) * 16 + lrow) * 512
                                    + (w & 1) * 32 + lchk * 8;
    unsigned short* al = &S.Albs[w & 1][(w >> 1) * 16][0];
    const unsigned short* wg[4];
    unsigned short* wl[4];
#pragma unroll
    for (int j = 0; j < 4; ++j) {
      int u = w * 4 + j;
      int kk = u & 1, rb = u >> 1;
      wg[j] = w_conv + (size_t)(rb * 16 + lrow) * 512 + kk * 32 + lchk * 8;
      wl[j] = &S.Wlds[kk][rb * 16][0];
    }
    for (int k0 = 0; k0 < 512; k0 += 64) {
      __syncthreads();
      gload16(ag + k0, al);
#pragma unroll
      for (int j = 0; j < 4; ++j) gload16(wg[j] + k0, wl[j]);
      __syncthreads();
#pragma unroll
      for (int kk = 0; kk < 2; ++kk) {
        bf16x8 af[2], bw[4];
#pragma unroll
        for (int ms = 0; ms < 2; ++ms)
          af[ms] = *(const bf16x8*)&S.Albs[kk][mw * 32 + ms * 16 + cl][g * 8];
#pragma unroll
        for (int ns = 0; ns < 4; ++ns)
          bw[ns] = *(const bf16x8*)&S.Wlds[kk][nw * 64 + ns * 16 + cl][g * 8];
#pragma unroll
        for (int ms = 0; ms < 2; ++ms)
#pragma unroll
          for (int ns = 0; ns < 4; ++ns)
            acc[ms][ns] = __builtin_amdgcn_mfma_f32_16x16x32_bf16(af[ms], bw[ns], acc[ms][ns], 0, 0, 0);
      }
    }
    // epilogue: bias + BN + pos -> X4L (bf16)
    const float is = 0.99999500003749968f;  // 1/sqrt(1+1e-5)
#pragma unroll
    for (int ns = 0; ns < 4; ++ns) {
      int col = nw * 64 + ns * 16 + cl;
      float bvv = conv_b[col];
      float gg = is * bn_g[col], b2 = bn_b[col];
      int c64off = ns * 16 + cl;
#pragma unroll
      for (int ms = 0; ms < 2; ++ms) {
#pragma unroll
        for (int i = 0; i < 4; ++i) {
          int rl = mw * 32 + ms * 16 + g * 4 + i;
          float v = acc[ms][ns][i] + bvv;
          float y = v * gg + b2 + posb[(size_t)(sbase + rl) * 256 + col];
          X4L[nw][c64off >> 5][rl][c64off & 31] = f2bf(y);
        }
      }
    }
    __syncthreads();   // X4L complete; Wlds free
  }

  // ---- phase 2: K = relu(LN(X4 @ k_w + k_b)) ----
  {
#pragma unroll
    for (int ms = 0; ms < 2; ++ms)
#pragma unroll
      for (int ns = 0; ns < 4; ++ns)
        acc[ms][ns] = (f32x4){0.f, 0.f, 0.f, 0.f};
    for (int c = 0; c < 4; ++c) {
      __syncthreads();
#pragma unroll
      for (int j = 0; j < 4; ++j) {
        int u = w * 4 + j;
        int kk = u & 1, rb = u >> 1;
        gload16(w_k + (size_t)(rb * 16 + lrow) * 256 + c * 64 + kk * 32 + lchk * 8,
                &S.Wlds[kk][rb * 16][0]);
      }
      __syncthreads();
#pragma unroll
      for (int kk = 0; kk < 2; ++kk) {
        bf16x8 af[2], bw[4];
#pragma unroll
        for (int ms = 0; ms < 2; ++ms)
          af[ms] = *(const bf16x8*)&X4L[c][kk][mw * 32 + ms * 16 + cl][g * 8];
#pragma unroll
        for (int ns = 0; ns < 4; ++ns)
          bw[ns] = *(const bf16x8*)&S.Wlds[kk][nw * 64 + ns * 16 + cl][g * 8];
#pragma unroll
        for (int ms = 0; ms < 2; ++ms)
#pragma unroll
          for (int ns = 0; ns < 4; ++ns)
            acc[ms][ns] = __builtin_amdgcn_mfma_f32_16x16x32_bf16(af[ms], bw[ns], acc[ms][ns], 0, 0, 0);
      }
    }
    float bv[4];
#pragma unroll
    for (int ns = 0; ns < 4; ++ns) bv[ns] = k_b[nw * 64 + ns * 16 + cl];
#pragma unroll
    for (int ms = 0; ms < 2; ++ms) {
#pragma unroll
      for (int i = 0; i < 4; ++i) {
        float p = 0.f, q = 0.f;
#pragma unroll
        for (int ns = 0; ns < 4; ++ns) {
          float v = acc[ms][ns][i] + bv[ns];
          p += v; q += v * v;
        }
        p += __shfl_xor(p, 1); q += __shfl_xor(q, 1);
        p += __shfl_xor(p, 2); q += __shfl_xor(q, 2);
        p += __shfl_xor(p, 4); q += __shfl_xor(q, 4);
        p += __shfl_xor(p, 8); q += __shfl_xor(q, 8);
        if (cl == 0) {
          int rl = mw * 32 + ms * 16 + g * 4 + i;
          S.part[nw][rl][0] = p;
          S.part[nw][rl][1] = q;
        }
      }
    }
    __syncthreads();
#pragma unroll
    for (int ms = 0; ms < 2; ++ms) {
#pragma unroll
      for (int i = 0; i < 4; ++i) {
        int rl = mw * 32 + ms * 16 + g * 4 + i;
        float sp = (S.part[0][rl][0] + S.part[1][rl][0]) + (S.part[2][rl][0] + S.part[3][rl][0]);
        float sq = (S.part[0][rl][1] + S.part[1][rl][1]) + (S.part[2][rl][1] + S.part[3][rl][1]);
        float mean = sp * (1.f / 256.f);
        float var = sq * (1.f / 256.f) - mean * mean;
        float inv = rsqrtf(var + 1e-5f);
#pragma unroll
        for (int ns = 0; ns < 4; ++ns) {
          int col = nw * 64 + ns * 16 + cl;
          float v = acc[ms][ns][i] + bv[ns];
          float y = (v - mean) * inv * k_g[col] + k_bt[col];
          Ko[(size_t)(t0 + rl) * 256 + col] = f2bf(fmaxf(y, 0.f));
        }
      }
    }
  }

  // ---- phase 3: V = X4 @ v_w + v_b ----
  {
#pragma unroll
    for (int ms = 0; ms < 2; ++ms)
#pragma unroll
      for (int ns = 0; ns < 4; ++ns)
        acc[ms][ns] = (f32x4){0.f, 0.f, 0.f, 0.f};
    for (int c = 0; c < 4; ++c) {
      __syncthreads();
#pragma unroll
      for (int j = 0; j < 4; ++j) {
        int u = w * 4 + j;
        int kk = u & 1, rb = u >> 1;
        gload16(w_v + (size_t)(rb * 16 + lrow) * 256 + c * 64 + kk * 32 + lchk * 8,
                &S.Wlds[kk][rb * 16][0]);
      }
      __syncthreads();
#pragma unroll
      for (int kk = 0; kk < 2; ++kk) {
        bf16x8 af[2], bw[4];
#pragma unroll
        for (int ms = 0; ms < 2; ++ms)
          af[ms] = *(const bf16x8*)&X4L[c][kk][mw * 32 + ms * 16 + cl][g * 8];
#pragma unroll
        for (int ns = 0; ns < 4; ++ns)
          bw[ns] = *(const bf16x8*)&S.Wlds[kk][nw * 64 + ns * 16 + cl][g * 8];
#pragma unroll
        for (int ms = 0; ms < 2; ++ms)
#pragma unroll
          for (int ns = 0; ns < 4; ++ns)
            acc[ms][ns] = __builtin_amdgcn_mfma_f32_16x16x32_bf16(af[ms], bw[ns], acc[ms][ns], 0, 0, 0);
      }
    }
#pragma unroll
    for (int ns = 0; ns < 4; ++ns) {
      int col = nw * 64 + ns * 16 + cl;
      float bvv = v_b[col];
#pragma unroll
      for (int ms = 0; ms < 2; ++ms)
#pragma unroll
        for (int i = 0; i < 4; ++i) {
          int rl = mw * 32 + ms * 16 + g * 4 + i;
          Vo[(size_t)(t0 + rl) * 256 + col] = f2bf(acc[ms][ns][i] + bvv);
        }
    }
  }
}

// Per (bh, s-split of 320): partial KV[d][e], Ksum[d]
__global__ __launch_bounds__(256) void kv_kernel(
    const unsigned short* __restrict__ Kb, const unsigned short* __restrict__ Vb,
    float* __restrict__ KVp, float* __restrict__ Ksp) {
  __shared__ float Kc[64][32];
  __shared__ float Vc[64][32];
  __shared__ float sv[64], cv[64];
  __shared__ float red[4][64];
  int bx = blockIdx.x;
  int bh = bx / 5, sp = bx - bh * 5;
  int b = bh >> 3, h = bh & 7;
  int tid = threadIdx.x;
  int e = tid & 31, dg = tid >> 5;
  int d4 = dg * 4;
  int dks = tid & 63, partid = tid >> 6;
  float accs[4] = {0.f, 0.f, 0.f, 0.f};
  float accc[4] = {0.f, 0.f, 0.f, 0.f};
  float ks = 0.f;
  size_t base = ((size_t)b * 1600) * 256 + h * 32;
  for (int s0 = sp * 320; s0 < sp * 320 + 320; s0 += 64) {
    __syncthreads();
#pragma unroll
    for (int p = 0; p < 8; ++p) {
      int si = dg + p * 8;
      Kc[si][e] = bf2f(Kb[base + (size_t)(s0 + si) * 256 + e]);
      Vc[si][e] = bf2f(Vb[base + (size_t)(s0 + si) * 256 + e]);
    }
    if (tid < 64) {
      float wv = 1.5707963267948966f * (float)(s0 + tid + 1) * (1.0f / 1600.0f);
      sv[tid] = sinf(wv);
      cv[tid] = cosf(wv);
    }
    __syncthreads();
#pragma unroll 8
    for (int si = 0; si < 64; ++si) {
      float vv = Vc[si][e];
      float sn = sv[si], cs = cv[si];
      float4 k4 = *(const float4*)&Kc[si][d4];
      float p0 = k4.x * vv, p1 = k4.y * vv, p2 = k4.z * vv, p3 = k4.w * vv;
      accs[0] = fmaf(p0, sn, accs[0]); accc[0] = fmaf(p0, cs, accc[0]);
      accs[1] = fmaf(p1, sn, accs[1]); accc[1] = fmaf(p1, cs, accc[1]);
      accs[2] = fmaf(p2, sn, accs[2]); accc[2] = fmaf(p2, cs, accc[2]);
      accs[3] = fmaf(p3, sn, accs[3]); accc[3] = fmaf(p3, cs, accc[3]);
    }
#pragma unroll 4
    for (int q = 0; q < 16; ++q) {
      int si = partid * 16 + q;
      float kvv = (dks < 32) ? Kc[si][dks] * sv[si] : Kc[si][dks - 32] * cv[si];
      ks += kvv;
    }
  }
  red[partid][dks] = ks;
  __syncthreads();
  size_t ob = (size_t)sp * 128 + bh;
  if (tid < 64)
    Ksp[ob * 64 + tid] = (red[0][tid] + red[1][tid]) + (red[2][tid] + red[3][tid]);
#pragma unroll
  for (int i = 0; i < 4; ++i) {
    KVp[ob * 2048 + (d4 + i) * 32 + e] = accs[i];
    KVp[ob * 2048 + (32 + d4 + i) * 32 + e] = accc[i];
  }
}

__global__ __launch_bounds__(256) void kvred_kernel(
    const float* __restrict__ KVp, const float* __restrict__ Ksp,
    float* __restrict__ KV, float* __restrict__ Ks) {
  int bh = blockIdx.x, tid = threadIdx.x;
  size_t o = (size_t)bh * 2048 + tid * 8;
  float4 s0 = make_float4(0, 0, 0, 0), s1 = make_float4(0, 0, 0, 0);
#pragma unroll
  for (int sp = 0; sp < 5; ++sp) {
    const float* p = KVp + ((size_t)sp * 128 + bh) * 2048 + tid * 8;
    float4 a = *(const float4*)p;
    float4 b2 = *(const float4*)(p + 4);
    s0.x += a.x; s0.y += a.y; s0.z += a.z; s0.w += a.w;
    s1.x += b2.x; s1.y += b2.y; s1.z += b2.z; s1.w += b2.w;
  }
  *(float4*)(KV + o) = s0;
  *(float4*)(KV + o + 4) = s1;
  if (tid < 64) {
    float t = 0.f;
#pragma unroll
    for (int sp = 0; sp < 5; ++sp) t += Ksp[((size_t)sp * 128 + bh) * 64 + tid];
    Ks[bh * 64 + tid] = t;
  }
}

// attn[t][h*32+e] bf16
__global__ __launch_bounds__(256) void attn_kernel(
    const unsigned short* __restrict__ Qb, const float* __restrict__ KV,
    const float* __restrict__ Ksum, unsigned short* __restrict__ attn) {
  int grp = threadIdx.x >> 5;
  int e = threadIdx.x & 31;
  int t = blockIdx.x * 8 + grp;
  int b = t / 1600, s = t - b * 1600;
  float wv = 1.5707963267948966f * (float)(s + 1) * (1.0f / 1600.0f);
  float sq = sinf(wv), cq = cosf(wv);
  const unsigned short* qrow = Qb + (size_t)t * 256;
  for (int h = 0; h < 8; ++h) {
    int bh = b * 8 + h;
    const float* kv = KV + (size_t)bh * 2048;
    const float* ksm = Ksum + (size_t)bh * 64;
    float qe = bf2f(qrow[h * 32 + e]);
    float zp = qe * (sq * ksm[e] + cq * ksm[32 + e]);
    zp += __shfl_xor(zp, 1); zp += __shfl_xor(zp, 2);
    zp += __shfl_xor(zp, 4); zp += __shfl_xor(zp, 8); zp += __shfl_xor(zp, 16);
    float acc = 0.f;
#pragma unroll 8
    for (int d = 0; d < 32; ++d) {
      float qv = bf2f(qrow[h * 32 + d]);
      acc = fmaf(qv * sq, kv[d * 32 + e], acc);
      acc = fmaf(qv * cq, kv[(32 + d) * 32 + e], acc);
    }
    float zc = fminf(fmaxf(zp, 1e-4f), 10.0f);
    attn[(size_t)t * 256 + h * 32 + e] = f2bf(acc * (1.0f / zc));
  }
}

// vectorized half-pixel 40->80 bilinear
__device__ __forceinline__ float4 up_row4(const float* sm, int Y, int q) {
  float fy = Y * 0.5f - 0.25f;
  int iy = (int)floorf(fy);
  float dy = fy - (float)iy;
  int y0 = iy < 0 ? 0 : iy;
  int y1 = (iy + 1) > 39 ? 39 : (iy + 1);
  const float* r0 = sm + y0 * 40;
  const float* r1 = sm + y1 * 40;
  int cm1 = (2 * q - 1) < 0 ? 0 : (2 * q - 1);
  int cp2 = (2 * q + 2) > 39 ? 39 : (2 * q + 2);
  float w1 = 1.f - dy;
  float s0 = w1 * r0[cm1]       + dy * r1[cm1];
  float s1 = w1 * r0[2 * q]     + dy * r1[2 * q];
  float s2 = w1 * r0[2 * q + 1] + dy * r1[2 * q + 1];
  float s3 = w1 * r0[cp2]       + dy * r1[cp2];
  float4 o;
  o.x = 0.25f * s0 + 0.75f * s1;
  o.y = 0.75f * s1 + 0.25f * s2;
  o.z = 0.25f * s1 + 0.75f * s2;
  o.w = 0.75f * s2 + 0.25f * s3;
  return o;
}

// fused upsamples: id<4096 -> bf16 a3p * a3 path, else fp32 a4 path
__global__ __launch_bounds__(256) void upsample_fused_kernel(
    const unsigned short* __restrict__ a3p, const float* __restrict__ a3,
    const float* __restrict__ a4, float* __restrict__ out0,
    float* __restrict__ out1) {
  __shared__ float sm[1600];
  int id = blockIdx.x;
  if (id < 4096) {
    int c = id & 255, b = id >> 8;
    const unsigned short* src = a3p + ((size_t)b * 256 + c) * 1600;
    float* outp = out0 + ((size_t)b * 256 + c) * 6400;
    const float* mul = a3 + ((size_t)b * 256 + c) * 6400;
    for (int i = threadIdx.x; i < 200; i += 256) {
      us8 v = *(const us8*)(src + i * 8);
#pragma unroll
      for (int j = 0; j < 8; ++j) sm[i * 8 + j] = bf2f(v[j]);
    }
    __syncthreads();
    for (int i = threadIdx.x; i < 1600; i += 256) {
      int Y = i / 20, q = i - Y * 20;
      float4 o = up_row4(sm, Y, q);
      float4 m = *(const float4*)(mul + i * 4);
      o.x *= m.x; o.y *= m.y; o.z *= m.z; o.w *= m.w;
      *(float4*)(outp + i * 4) = o;
    }
  } else {
    int id2 = id - 4096;
    int c = id2 & 511, b = id2 >> 9;
    const float* src = a4 + ((size_t)b * 512 + c) * 1600;
    float* outp = out1 + ((size_t)b * 512 + c) * 6400;
    for (int i = threadIdx.x; i < 400; i += 256)
      *(float4*)&sm[i * 4] = *(const float4*)(src + i * 4);
    __syncthreads();
    for (int i = threadIdx.x; i < 1600; i += 256) {
      int Y = i / 20, q = i - Y * 20;
      float4 o = up_row4(sm, Y, q);
      *(float4*)(outp + i * 4) = o;
    }
  }
}

extern "C" void kernel_launch(void* const* d_in, const int* in_sizes, int n_in,
                              void* d_out, int out_size, void* d_ws, size_t ws_size,
                              hipStream_t stream) {
  const float* a3     = (const float*)d_in[0];
  const float* a4     = (const float*)d_in[1];
  const float* conv_w = (const float*)d_in[2];
  const float* conv_b = (const float*)d_in[3];
  const float* bn_g   = (const float*)d_in[4];
  const float* bn_b   = (const float*)d_in[5];
  const float* q_w    = (const float*)d_in[6];
  const float* q_b    = (const float*)d_in[7];
  const float* q_ln_g = (const float*)d_in[8];
  const float* q_ln_b = (const float*)d_in[9];
  const float* k_w    = (const float*)d_in[10];
  const float* k_b    = (const float*)d_in[11];
  const float* k_ln_g = (const float*)d_in[12];
  const float* k_ln_b = (const float*)d_in[13];
  const float* v_w    = (const float*)d_in[14];
  const float* v_b    = (const float*)d_in[15];
  const float* out_w  = (const float*)d_in[16];
  const float* out_b  = (const float*)d_in[17];
  const float* lin1_w = (const float*)d_in[18];
  const float* lin1_b = (const float*)d_in[19];
  const float* lin2_w = (const float*)d_in[20];
  const float* lin2_b = (const float*)d_in[21];
  const float* n1_g   = (const float*)d_in[22];
  const float* n1_b   = (const float*)d_in[23];
  const float* n2_g   = (const float*)d_in[24];
  const float* n2_b   = (const float*)d_in[25];
  (void)in_sizes; (void)n_in; (void)out_size; (void)ws_size;

  float* ws = (float*)d_ws;
  float* pos  = ws + 0;
  unsigned short* wbf = (unsigned short*)(ws + 409600);
  float* KV   = ws + 868352;
  float* Ks   = ws + 1130496;
  float* KVp  = ws + 1138688;
  float* Ksp  = ws + 2449408;
  unsigned short* X3b  = (unsigned short*)(ws + 2490368);
  unsigned short* Qbb  = (unsigned short*)(ws + 9043968);
  unsigned short* Kbb  = (unsigned short*)(ws + 12320768);  // -> attn
  unsigned short* Vbb  = (unsigned short*)(ws + 15597568);
  unsigned short* o1b  = (unsigned short*)(ws + 18874368);
  unsigned short* a4tb = (unsigned short*)(ws + 22151168);  // dead after convkv
  unsigned short* ffhb = (unsigned short*)(ws + 22151168);
  unsigned short* a3p  = (unsigned short*)(ws + 9043968);  // bf16 [b][c][40][40]; reuses QB

  const unsigned short* w_conv = wbf;
  const unsigned short* w_q    = wbf + 131072;
  const unsigned short* w_k    = wbf + 196608;
  const unsigned short* w_v    = wbf + 262144;
  const unsigned short* w_o    = wbf + 327680;
  const unsigned short* w_l1   = wbf + 393216;
  const unsigned short* w_l2   = wbf + 655360;

  float* out0 = (float*)d_out;
  float* out1f = out0 + (size_t)16 * 256 * 80 * 80;

  prep_kernel<<<5248, 256, 0, stream>>>(conv_w, q_w, k_w, v_w, out_w, lin1_w, lin2_w,
                                        wbf, pos, a4, a4tb);
  avgpool_kernel<<<dim3(40, 16), 640, 0, stream>>>(a3, pos, X3b);
  // conv + BN + pos -> X4 (LDS-resident) -> K, V
  convkv_kernel<<<400, 512, 0, stream>>>(a4tb, w_conv, w_k, w_v,
      conv_b, k_b, v_b, bn_g, bn_b, pos, k_ln_g, k_ln_b, Kbb, Vbb);
  // Q = relu(LN(X3 @ qw + qb))
  fgemm<2><<<dim3(400, 1), 512, 0, stream>>>(X3b, w_q, q_b, Qbb, 256, 256, nullptr, q_ln_g, q_ln_b, nullptr);
  // linear attention
  kv_kernel<<<640, 256, 0, stream>>>(Kbb, Vbb, KVp, Ksp);
  kvred_kernel<<<128, 256, 0, stream>>>(KVp, Ksp, KV, Ks);
  attn_kernel<<<3200, 256, 0, stream>>>(Qbb, KV, Ks, Kbb /*attn*/);
  // out1 = (X3-pos) + LN1(attn @ ow + ob)   -> o1b (bf16)
  fgemm<3><<<dim3(400, 1), 512, 0, stream>>>(Kbb, w_o, out_b, o1b, 256, 256, pos, n1_g, n1_b, X3b);
  // ffh = gelu(out1 @ l1w + l1b)
  fgemm<4><<<dim3(400, 4), 512, 0, stream>>>(o1b, w_l1, lin1_b, ffhb, 256, 1024, nullptr, nullptr, nullptr, nullptr);
  // out2 = out1 + LN2(ffh @ l2w + l2b), written as [b][c][40][40] bf16
  fgemm<5><<<dim3(400, 1), 512, 0, stream>>>(ffhb, w_l2, lin2_b, a3p, 1024, 256, nullptr, n2_g, n2_b, o1b);
  // fused upsample: out0 = up(a3p)*a3 ; out1 = up(a4)
  upsample_fused_kernel<<<12288, 256, 0, stream>>>(a3p, a3, a4, out0, out1f);
}

// Round 11
// 366.401 us; speedup vs baseline: 1.0180x; 1.0180x over previous
//
#include <hip/hip_runtime.h>
#include <math.h>

// ---------------------------------------------------------------------------
// Round 11: R9 structure (conv fgemm + 1200-block fused QKV, BK=64 8-wave
//           bodies) + R10's verified a3p-bf16 (EPI5 bf16 store, bf16 upsample).
// Shapes (idx==10): bs=16, c=256, h=w=40, S=1600, T=25600, heads=8, hd=32
// ws float-offsets:
//   POS 0 | WBF 409600(bf16 weights) | KV 868352 | KS 1130496 | KVP 1138688
//   KSP 2449408 | X3bf 2490368 | X4bf 5767168 | QBbf 9043968 | KBbf 12320768
//   VBbf 15597568 | OUT1bf 18874368 | A4T/FFHbf 22151168 (.. 35258368)
//   A3P bf16 [b][c][40][40] at 9043968 (reuses QB, dead by lin2)
// ---------------------------------------------------------------------------

typedef __attribute__((ext_vector_type(8))) short bf16x8;
typedef __attribute__((ext_vector_type(8))) unsigned short us8;
typedef __attribute__((ext_vector_type(4))) unsigned short us4h;
typedef __attribute__((ext_vector_type(4))) float f32x4;

__device__ __forceinline__ unsigned short f2bf(float f) {
  unsigned int u = __float_as_uint(f);
  u += 0x7fff + ((u >> 16) & 1);  // RNE
  return (unsigned short)(u >> 16);
}
__device__ __forceinline__ float bf2f(unsigned short u) {
  return __uint_as_float(((unsigned int)u) << 16);
}

// async global->LDS, 16B per lane; LDS dest = wave-uniform base + lane*16
__device__ __forceinline__ void gload16(const void* g, void* l) {
  __builtin_amdgcn_global_load_lds(
      (const __attribute__((address_space(1))) void*)g,
      (__attribute__((address_space(3))) void*)l, 16, 0, 0);
}

// --- prep: [0,448) weights->bf16 ; [448,2048) pos ; [2048,5248) a4 transpose ---
__global__ __launch_bounds__(256) void prep_kernel(
    const float* __restrict__ cw, const float* __restrict__ qw,
    const float* __restrict__ kw, const float* __restrict__ vw,
    const float* __restrict__ ow, const float* __restrict__ l1w,
    const float* __restrict__ l2w, unsigned short* __restrict__ wbf,
    float* __restrict__ pos,
    const float* __restrict__ a4, unsigned short* __restrict__ a4t) {
  __shared__ float buf[64][65];
  if (blockIdx.x < 448) {
    int gid = blockIdx.x * 256 + threadIdx.x;
    size_t e0 = (size_t)gid * 8;
    const float* src; size_t off;
    if (e0 < 131072)      { src = cw;  off = e0; }
    else if (e0 < 196608) { src = qw;  off = e0 - 131072; }
    else if (e0 < 262144) { src = kw;  off = e0 - 196608; }
    else if (e0 < 327680) { src = vw;  off = e0 - 262144; }
    else if (e0 < 393216) { src = ow;  off = e0 - 327680; }
    else if (e0 < 655360) { src = l1w; off = e0 - 393216; }
    else                  { src = l2w; off = e0 - 655360; }
    float4 v0 = *(const float4*)(src + off);
    float4 v1 = *(const float4*)(src + off + 4);
    us8 r;
    r[0] = f2bf(v0.x); r[1] = f2bf(v0.y); r[2] = f2bf(v0.z); r[3] = f2bf(v0.w);
    r[4] = f2bf(v1.x); r[5] = f2bf(v1.y); r[6] = f2bf(v1.z); r[7] = f2bf(v1.w);
    *(us8*)(wbf + e0) = r;
  } else if (blockIdx.x < 2048) {
    int s = blockIdx.x - 448, c = threadIdx.x;
    int y = s / 40, x = s - y * 40;
    int quad = c >> 6, i = c & 63;
    float omega = expf(-(float)i * (9.2103403719761836f / 64.0f));
    float coord = (quad < 2) ? (float)y : (float)x;
    float a = coord * omega;
    pos[s * 256 + c] = (quad & 1) ? cosf(a) : sinf(a);
  } else {
    int id = blockIdx.x - 2048;          // 0..3199
    int b = id / 200;
    int r = id - b * 200;
    int s0 = (r % 25) * 64, k0 = (r / 25) * 64;
    const float* src = a4 + ((size_t)b * 512 + k0) * 1600 + s0;
#pragma unroll
    for (int p = 0; p < 4; ++p) {
      int idx = p * 256 + threadIdx.x;
      int kk = idx >> 4, s4 = (idx & 15) * 4;
      float4 v = *(const float4*)(src + (size_t)kk * 1600 + s4);
      buf[kk][s4 + 0] = v.x; buf[kk][s4 + 1] = v.y;
      buf[kk][s4 + 2] = v.z; buf[kk][s4 + 3] = v.w;
    }
    __syncthreads();
    unsigned short* dst = a4t + ((size_t)b * 1600 + s0) * 512 + k0;
#pragma unroll
    for (int p = 0; p < 4; ++p) {
      int idx = p * 256 + threadIdx.x;
      int ss = idx >> 4, kq = (idx & 15) * 4;
      us4h v;
      v[0] = f2bf(buf[kq + 0][ss]); v[1] = f2bf(buf[kq + 1][ss]);
      v[2] = f2bf(buf[kq + 2][ss]); v[3] = f2bf(buf[kq + 3][ss]);
      *(us4h*)(dst + (size_t)ss * 512 + kq) = v;
    }
  }
}

// a3 (b,c,80,80) -> X3bf[t][c] = avgpool2 + pos (bf16)
__global__ __launch_bounds__(640) void avgpool_kernel(
    const float* __restrict__ a3, const float* __restrict__ pos,
    unsigned short* __restrict__ X3) {
  __shared__ float buf2[256][44];
  int y = blockIdx.x, b = blockIdx.y;
  int tid = threadIdx.x;
  int x2 = tid % 20, cq = tid / 20;
#pragma unroll
  for (int it = 0; it < 8; ++it) {
    int c = cq + 32 * it;
    const float* p = a3 + (((size_t)(b * 256 + c) * 80 + 2 * y) * 80 + x2 * 4);
    float4 r0 = *(const float4*)p;
    float4 r1 = *(const float4*)(p + 80);
    buf2[c][2 * x2]     = 0.25f * ((r0.x + r0.y) + (r1.x + r1.y));
    buf2[c][2 * x2 + 1] = 0.25f * ((r0.z + r0.w) + (r1.z + r1.w));
  }
  __syncthreads();
  size_t t0 = (size_t)b * 1600 + y * 40;
  int sbase = y * 40;
#pragma unroll
  for (int it = 0; it < 4; ++it) {
    int idx = it * 640 + tid;
    int c = idx & 255, xq = idx >> 8;
    int x0 = xq * 4;
    float4 v = *(const float4*)&buf2[c][x0];
#pragma unroll
    for (int j = 0; j < 4; ++j) {
      float pv = pos[(size_t)(sbase + x0 + j) * 256 + c];
      float vv = (j == 0) ? v.x : (j == 1) ? v.y : (j == 2) ? v.z : v.w;
      X3[(t0 + x0 + j) * 256 + c] = f2bf(vv + pv);
    }
  }
}

// ---------------------------------------------------------------------------
// gemm_body (8 waves / 512 thr): BM=64, BN=256, BK=64; wave-tile 32x64.
// Two K-half subtiles keep LDS rows at 64B (no 128B-row bank conflict).
// EPI: 0 plain->bf16, 1 conv BN+pos->bf16, 2 LN+ReLU->bf16,
//      3 LN + (X3-pos) residual ->bf16, 4 GELU->bf16,
//      5 LN + out1 residual -> BF16 stored TRANSPOSED as [b][c][s]
// ---------------------------------------------------------------------------
struct __align__(16) SmemT {
  unsigned short Albs[2][64][32];
  unsigned short Wlds[2][256][32];
  float part[4][64][2];
};

template<int EPI>
__device__ __forceinline__ void gemm_body(
    SmemT& S,
    const unsigned short* __restrict__ A, const unsigned short* __restrict__ W,
    const float* __restrict__ bias, void* __restrict__ outp,
    const int K, const int ldN, int t0, int o0,
    const float* __restrict__ posb,
    const float* __restrict__ g1, const float* __restrict__ b1,
    const unsigned short* __restrict__ res) {
  int tid = threadIdx.x;
  int lane = tid & 63, w = tid >> 6;      // 8 waves
  int mw = w >> 2, nw = w & 3;
  int g = lane >> 4, cl = lane & 15;
  f32x4 acc[2][4] = {};

  int lrow = lane >> 2, lchk = lane & 3;
  const unsigned short* ag = A + (size_t)(t0 + (w >> 1) * 16 + lrow) * K
                               + (w & 1) * 32 + lchk * 8;
  unsigned short* al = &S.Albs[w & 1][(w >> 1) * 16][0];
  const unsigned short* wg[4];
  unsigned short* wl[4];
#pragma unroll
  for (int j = 0; j < 4; ++j) {
    int u = w * 4 + j;
    int kk = u & 1, rb = u >> 1;
    wg[j] = W + (size_t)(o0 + rb * 16 + lrow) * K + kk * 32 + lchk * 8;
    wl[j] = &S.Wlds[kk][rb * 16][0];
  }

  for (int k0 = 0; k0 < K; k0 += 64) {
    __syncthreads();
    gload16(ag + k0, al);
#pragma unroll
    for (int j = 0; j < 4; ++j) gload16(wg[j] + k0, wl[j]);
    __syncthreads();
#pragma unroll
    for (int kk = 0; kk < 2; ++kk) {
      bf16x8 af[2], bw[4];
#pragma unroll
      for (int ms = 0; ms < 2; ++ms)
        af[ms] = *(const bf16x8*)&S.Albs[kk][mw * 32 + ms * 16 + cl][g * 8];
#pragma unroll
      for (int ns = 0; ns < 4; ++ns)
        bw[ns] = *(const bf16x8*)&S.Wlds[kk][nw * 64 + ns * 16 + cl][g * 8];
#pragma unroll
      for (int ms = 0; ms < 2; ++ms)
#pragma unroll
        for (int ns = 0; ns < 4; ++ns)
          acc[ms][ns] = __builtin_amdgcn_mfma_f32_16x16x32_bf16(af[ms], bw[ns], acc[ms][ns], 0, 0, 0);
    }
  }

  float bv[4];
#pragma unroll
  for (int ns = 0; ns < 4; ++ns) bv[ns] = bias[o0 + nw * 64 + ns * 16 + cl];
  int sbase = t0 % 1600;  // 1600 % 64 == 0: block never crosses batch

  if constexpr (EPI == 2 || EPI == 3 || EPI == 5) {
#pragma unroll
    for (int ms = 0; ms < 2; ++ms) {
#pragma unroll
      for (int i = 0; i < 4; ++i) {
        float p = 0.f, q = 0.f;
#pragma unroll
        for (int ns = 0; ns < 4; ++ns) {
          float v = acc[ms][ns][i] + bv[ns];
          p += v; q += v * v;
        }
        p += __shfl_xor(p, 1); q += __shfl_xor(q, 1);
        p += __shfl_xor(p, 2); q += __shfl_xor(q, 2);
        p += __shfl_xor(p, 4); q += __shfl_xor(q, 4);
        p += __shfl_xor(p, 8); q += __shfl_xor(q, 8);
        if (cl == 0) {
          int rl = mw * 32 + ms * 16 + g * 4 + i;
          S.part[nw][rl][0] = p;
          S.part[nw][rl][1] = q;
        }
      }
    }
    __syncthreads();
  }

  if constexpr (EPI == 5) {
    // LN2 + residual, stored transposed BF16: out[b][col][s]
    unsigned short* ob2 = (unsigned short*)outp;
    int bb = t0 / 1600;
#pragma unroll
    for (int ms = 0; ms < 2; ++ms) {
      int rl0 = mw * 32 + ms * 16 + g * 4;
      float mean[4], inv[4];
#pragma unroll
      for (int i = 0; i < 4; ++i) {
        float sp = (S.part[0][rl0 + i][0] + S.part[1][rl0 + i][0]) +
                   (S.part[2][rl0 + i][0] + S.part[3][rl0 + i][0]);
        float sq = (S.part[0][rl0 + i][1] + S.part[1][rl0 + i][1]) +
                   (S.part[2][rl0 + i][1] + S.part[3][rl0 + i][1]);
        mean[i] = sp * (1.f / 256.f);
        float var = sq * (1.f / 256.f) - mean[i] * mean[i];
        inv[i] = rsqrtf(var + 1e-5f);
      }
#pragma unroll
      for (int ns = 0; ns < 4; ++ns) {
        int col = nw * 64 + ns * 16 + cl;
        float gg = g1[col], b2 = b1[col];
        us4h y;
#pragma unroll
        for (int i = 0; i < 4; ++i) {
          float v = acc[ms][ns][i] + bv[ns];
          float yy = (v - mean[i]) * inv[i] * gg + b2;
          yy += bf2f(res[(size_t)(t0 + rl0 + i) * 256 + col]);
          y[i] = f2bf(yy);
        }
        *(us4h*)(ob2 + ((size_t)(bb * 256 + col) * 1600) + sbase + rl0) = y;
      }
    }
    return;
  }

  unsigned short* ob = (unsigned short*)outp;
#pragma unroll
  for (int ms = 0; ms < 2; ++ms) {
#pragma unroll
    for (int i = 0; i < 4; ++i) {
      int rl = mw * 32 + ms * 16 + g * 4 + i;
      int t = t0 + rl;
      float mean = 0.f, inv = 0.f;
      if constexpr (EPI == 2 || EPI == 3) {
        float sp = (S.part[0][rl][0] + S.part[1][rl][0]) + (S.part[2][rl][0] + S.part[3][rl][0]);
        float sq = (S.part[0][rl][1] + S.part[1][rl][1]) + (S.part[2][rl][1] + S.part[3][rl][1]);
        mean = sp * (1.f / 256.f);
        float var = sq * (1.f / 256.f) - mean * mean;
        inv = rsqrtf(var + 1e-5f);
      }
#pragma unroll
      for (int ns = 0; ns < 4; ++ns) {
        int col = nw * 64 + ns * 16 + cl;
        float v = acc[ms][ns][i] + bv[ns];
        size_t oidx = (size_t)t * ldN + o0 + col;
        if constexpr (EPI == 0) {
          ob[oidx] = f2bf(v);
        } else if constexpr (EPI == 1) {
          const float is = 0.99999500003749968f;  // 1/sqrt(1+1e-5)
          float y = v * (is * g1[col]) + b1[col] + posb[(size_t)(sbase + rl) * 256 + col];
          ob[oidx] = f2bf(y);
        } else if constexpr (EPI == 2) {
          float y = (v - mean) * inv * g1[col] + b1[col];
          ob[oidx] = f2bf(fmaxf(y, 0.f));
        } else if constexpr (EPI == 3) {
          float y = (v - mean) * inv * g1[col] + b1[col];
          y += bf2f(res[(size_t)t * 256 + col]) - posb[(size_t)(sbase + rl) * 256 + col];
          ob[oidx] = f2bf(y);
        } else if constexpr (EPI == 4) {
          float y = 0.5f * v * (1.f + erff(v * 0.7071067811865475f));
          ob[oidx] = f2bf(y);
        }
      }
    }
  }
}

template<int EPI>
__global__ __launch_bounds__(512) void fgemm(
    const unsigned short* __restrict__ A, const unsigned short* __restrict__ W,
    const float* __restrict__ bias, void* __restrict__ outp,
    const int K, const int ldN,
    const float* __restrict__ posb,
    const float* __restrict__ g1, const float* __restrict__ b1,
    const unsigned short* __restrict__ res) {
  __shared__ SmemT S;
  gemm_body<EPI>(S, A, W, bias, outp, K, ldN, blockIdx.x * 64, blockIdx.y * 256,
                 posb, g1, b1, res);
}

// fused QKV: blockIdx.y = 0:Q(LN+ReLU), 1:K(LN+ReLU), 2:V(plain); o0=0 for all
__global__ __launch_bounds__(512) void qkv_kernel(
    const unsigned short* __restrict__ X3b, const unsigned short* __restrict__ X4b,
    const unsigned short* __restrict__ w_q, const unsigned short* __restrict__ w_k,
    const unsigned short* __restrict__ w_v,
    const float* __restrict__ q_b, const float* __restrict__ k_b, const float* __restrict__ v_b,
    const float* __restrict__ q_g, const float* __restrict__ q_bt,
    const float* __restrict__ k_g, const float* __restrict__ k_bt,
    unsigned short* __restrict__ Qo, unsigned short* __restrict__ Ko,
    unsigned short* __restrict__ Vo) {
  __shared__ SmemT S;
  int t0 = blockIdx.x * 64;
  if (blockIdx.y == 0) {
    gemm_body<2>(S, X3b, w_q, q_b, Qo, 256, 256, t0, 0, nullptr, q_g, q_bt, nullptr);
  } else if (blockIdx.y == 1) {
    gemm_body<2>(S, X4b, w_k, k_b, Ko, 256, 256, t0, 0, nullptr, k_g, k_bt, nullptr);
  } else {
    gemm_body<0>(S, X4b, w_v, v_b, Vo, 256, 256, t0, 0, nullptr, nullptr, nullptr, nullptr);
  }
}

// Per (bh, s-split of 320): partial KV[d][e], Ksum[d]
__global__ __launch_bounds__(256) void kv_kernel(
    const unsigned short* __restrict__ Kb, const unsigned short* __restrict__ Vb,
    float* __restrict__ KVp, float* __restrict__ Ksp) {
  __shared__ float Kc[64][32];
  __shared__ float Vc[64][32];
  __shared__ float sv[64], cv[64];
  __shared__ float red[4][64];
  int bx = blockIdx.x;
  int bh = bx / 5, sp = bx - bh * 5;
  int b = bh >> 3, h = bh & 7;
  int tid = threadIdx.x;
  int e = tid & 31, dg = tid >> 5;
  int d4 = dg * 4;
  int dks = tid & 63, partid = tid >> 6;
  float accs[4] = {0.f, 0.f, 0.f, 0.f};
  float accc[4] = {0.f, 0.f, 0.f, 0.f};
  float ks = 0.f;
  size_t base = ((size_t)b * 1600) * 256 + h * 32;
  for (int s0 = sp * 320; s0 < sp * 320 + 320; s0 += 64) {
    __syncthreads();
#pragma unroll
    for (int p = 0; p < 8; ++p) {
      int si = dg + p * 8;
      Kc[si][e] = bf2f(Kb[base + (size_t)(s0 + si) * 256 + e]);
      Vc[si][e] = bf2f(Vb[base + (size_t)(s0 + si) * 256 + e]);
    }
    if (tid < 64) {
      float wv = 1.5707963267948966f * (float)(s0 + tid + 1) * (1.0f / 1600.0f);
      sv[tid] = sinf(wv);
      cv[tid] = cosf(wv);
    }
    __syncthreads();
#pragma unroll 8
    for (int si = 0; si < 64; ++si) {
      float vv = Vc[si][e];
      float sn = sv[si], cs = cv[si];
      float4 k4 = *(const float4*)&Kc[si][d4];
      float p0 = k4.x * vv, p1 = k4.y * vv, p2 = k4.z * vv, p3 = k4.w * vv;
      accs[0] = fmaf(p0, sn, accs[0]); accc[0] = fmaf(p0, cs, accc[0]);
      accs[1] = fmaf(p1, sn, accs[1]); accc[1] = fmaf(p1, cs, accc[1]);
      accs[2] = fmaf(p2, sn, accs[2]); accc[2] = fmaf(p2, cs, accc[2]);
      accs[3] = fmaf(p3, sn, accs[3]); accc[3] = fmaf(p3, cs, accc[3]);
    }
#pragma unroll 4
    for (int q = 0; q < 16; ++q) {
      int si = partid * 16 + q;
      float kvv = (dks < 32) ? Kc[si][dks] * sv[si] : Kc[si][dks - 32] * cv[si];
      ks += kvv;
    }
  }
  red[partid][dks] = ks;
  __syncthreads();
  size_t ob = (size_t)sp * 128 + bh;
  if (tid < 64)
    Ksp[ob * 64 + tid] = (red[0][tid] + red[1][tid]) + (red[2][tid] + red[3][tid]);
#pragma unroll
  for (int i = 0; i < 4; ++i) {
    KVp[ob * 2048 + (d4 + i) * 32 + e] = accs[i];
    KVp[ob * 2048 + (32 + d4 + i) * 32 + e] = accc[i];
  }
}

__global__ __launch_bounds__(256) void kvred_kernel(
    const float* __restrict__ KVp, const float* __restrict__ Ksp,
    float* __restrict__ KV, float* __restrict__ Ks) {
  int bh = blockIdx.x, tid = threadIdx.x;
  size_t o = (size_t)bh * 2048 + tid * 8;
  float4 s0 = make_float4(0, 0, 0, 0), s1 = make_float4(0, 0, 0, 0);
#pragma unroll
  for (int sp = 0; sp < 5; ++sp) {
    const float* p = KVp + ((size_t)sp * 128 + bh) * 2048 + tid * 8;
    float4 a = *(const float4*)p;
    float4 b2 = *(const float4*)(p + 4);
    s0.x += a.x; s0.y += a.y; s0.z += a.z; s0.w += a.w;
    s1.x += b2.x; s1.y += b2.y; s1.z += b2.z; s1.w += b2.w;
  }
  *(float4*)(KV + o) = s0;
  *(float4*)(KV + o + 4) = s1;
  if (tid < 64) {
    float t = 0.f;
#pragma unroll
    for (int sp = 0; sp < 5; ++sp) t += Ksp[((size_t)sp * 128 + bh) * 64 + tid];
    Ks[bh * 64 + tid] = t;
  }
}

// attn[t][h*32+e] bf16
__global__ __launch_bounds__(256) void attn_kernel(
    const unsigned short* __restrict__ Qb, const float* __restrict__ KV,
    const float* __restrict__ Ksum, unsigned short* __restrict__ attn) {
  int grp = threadIdx.x >> 5;
  int e = threadIdx.x & 31;
  int t = blockIdx.x * 8 + grp;
  int b = t / 1600, s = t - b * 1600;
  float wv = 1.5707963267948966f * (float)(s + 1) * (1.0f / 1600.0f);
  float sq = sinf(wv), cq = cosf(wv);
  const unsigned short* qrow = Qb + (size_t)t * 256;
  for (int h = 0; h < 8; ++h) {
    int bh = b * 8 + h;
    const float* kv = KV + (size_t)bh * 2048;
    const float* ksm = Ksum + (size_t)bh * 64;
    float qe = bf2f(qrow[h * 32 + e]);
    float zp = qe * (sq * ksm[e] + cq * ksm[32 + e]);
    zp += __shfl_xor(zp, 1); zp += __shfl_xor(zp, 2);
    zp += __shfl_xor(zp, 4); zp += __shfl_xor(zp, 8); zp += __shfl_xor(zp, 16);
    float acc = 0.f;
#pragma unroll 8
    for (int d = 0; d < 32; ++d) {
      float qv = bf2f(qrow[h * 32 + d]);
      acc = fmaf(qv * sq, kv[d * 32 + e], acc);
      acc = fmaf(qv * cq, kv[(32 + d) * 32 + e], acc);
    }
    float zc = fminf(fmaxf(zp, 1e-4f), 10.0f);
    attn[(size_t)t * 256 + h * 32 + e] = f2bf(acc * (1.0f / zc));
  }
}

// vectorized half-pixel 40->80 bilinear
__device__ __forceinline__ float4 up_row4(const float* sm, int Y, int q) {
  float fy = Y * 0.5f - 0.25f;
  int iy = (int)floorf(fy);
  float dy = fy - (float)iy;
  int y0 = iy < 0 ? 0 : iy;
  int y1 = (iy + 1) > 39 ? 39 : (iy + 1);
  const float* r0 = sm + y0 * 40;
  const float* r1 = sm + y1 * 40;
  int cm1 = (2 * q - 1) < 0 ? 0 : (2 * q - 1);
  int cp2 = (2 * q + 2) > 39 ? 39 : (2 * q + 2);
  float w1 = 1.f - dy;
  float s0 = w1 * r0[cm1]       + dy * r1[cm1];
  float s1 = w1 * r0[2 * q]     + dy * r1[2 * q];
  float s2 = w1 * r0[2 * q + 1] + dy * r1[2 * q + 1];
  float s3 = w1 * r0[cp2]       + dy * r1[cp2];
  float4 o;
  o.x = 0.25f * s0 + 0.75f * s1;
  o.y = 0.75f * s1 + 0.25f * s2;
  o.z = 0.25f * s1 + 0.75f * s2;
  o.w = 0.75f * s2 + 0.25f * s3;
  return o;
}

// fused upsamples: id<4096 -> bf16 a3p * a3 path, else fp32 a4 path
__global__ __launch_bounds__(256) void upsample_fused_kernel(
    const unsigned short* __restrict__ a3p, const float* __restrict__ a3,
    const float* __restrict__ a4, float* __restrict__ out0,
    float* __restrict__ out1) {
  __shared__ float sm[1600];
  int id = blockIdx.x;
  if (id < 4096) {
    int c = id & 255, b = id >> 8;
    const unsigned short* src = a3p + ((size_t)b * 256 + c) * 1600;
    float* outp = out0 + ((size_t)b * 256 + c) * 6400;
    const float* mul = a3 + ((size_t)b * 256 + c) * 6400;
    for (int i = threadIdx.x; i < 200; i += 256) {
      us8 v = *(const us8*)(src + i * 8);
#pragma unroll
      for (int j = 0; j < 8; ++j) sm[i * 8 + j] = bf2f(v[j]);
    }
    __syncthreads();
    for (int i = threadIdx.x; i < 1600; i += 256) {
      int Y = i / 20, q = i - Y * 20;
      float4 o = up_row4(sm, Y, q);
      float4 m = *(const float4*)(mul + i * 4);
      o.x *= m.x; o.y *= m.y; o.z *= m.z; o.w *= m.w;
      *(float4*)(outp + i * 4) = o;
    }
  } else {
    int id2 = id - 4096;
    int c = id2 & 511, b = id2 >> 9;
    const float* src = a4 + ((size_t)b * 512 + c) * 1600;
    float* outp = out1 + ((size_t)b * 512 + c) * 6400;
    for (int i = threadIdx.x; i < 400; i += 256)
      *(float4*)&sm[i * 4] = *(const float4*)(src + i * 4);
    __syncthreads();
    for (int i = threadIdx.x; i < 1600; i += 256) {
      int Y = i / 20, q = i - Y * 20;
      float4 o = up_row4(sm, Y, q);
      *(float4*)(outp + i * 4) = o;
    }
  }
}

extern "C" void kernel_launch(void* const* d_in, const int* in_sizes, int n_in,
                              void* d_out, int out_size, void* d_ws, size_t ws_size,
                              hipStream_t stream) {
  const float* a3     = (const float*)d_in[0];
  const float* a4     = (const float*)d_in[1];
  const float* conv_w = (const float*)d_in[2];
  const float* conv_b = (const float*)d_in[3];
  const float* bn_g   = (const float*)d_in[4];
  const float* bn_b   = (const float*)d_in[5];
  const float* q_w    = (const float*)d_in[6];
  const float* q_b    = (const float*)d_in[7];
  const float* q_ln_g = (const float*)d_in[8];
  const float* q_ln_b = (const float*)d_in[9];
  const float* k_w    = (const float*)d_in[10];
  const float* k_b    = (const float*)d_in[11];
  const float* k_ln_g = (const float*)d_in[12];
  const float* k_ln_b = (const float*)d_in[13];
  const float* v_w    = (const float*)d_in[14];
  const float* v_b    = (const float*)d_in[15];
  const float* out_w  = (const float*)d_in[16];
  const float* out_b  = (const float*)d_in[17];
  const float* lin1_w = (const float*)d_in[18];
  const float* lin1_b = (const float*)d_in[19];
  const float* lin2_w = (const float*)d_in[20];
  const float* lin2_b = (const float*)d_in[21];
  const float* n1_g   = (const float*)d_in[22];
  const float* n1_b   = (const float*)d_in[23];
  const float* n2_g   = (const float*)d_in[24];
  const float* n2_b   = (const float*)d_in[25];
  (void)in_sizes; (void)n_in; (void)out_size; (void)ws_size;

  float* ws = (float*)d_ws;
  float* pos  = ws + 0;
  unsigned short* wbf = (unsigned short*)(ws + 409600);
  float* KV   = ws + 868352;
  float* Ks   = ws + 1130496;
  float* KVp  = ws + 1138688;
  float* Ksp  = ws + 2449408;
  unsigned short* X3b  = (unsigned short*)(ws + 2490368);
  unsigned short* X4b  = (unsigned short*)(ws + 5767168);
  unsigned short* Qbb  = (unsigned short*)(ws + 9043968);
  unsigned short* Kbb  = (unsigned short*)(ws + 12320768);  // -> attn
  unsigned short* Vbb  = (unsigned short*)(ws + 15597568);
  unsigned short* o1b  = (unsigned short*)(ws + 18874368);
  unsigned short* a4tb = (unsigned short*)(ws + 22151168);  // dead after conv
  unsigned short* ffhb = (unsigned short*)(ws + 22151168);
  unsigned short* a3p  = (unsigned short*)(ws + 9043968);  // bf16 [b][c][40][40]; reuses QB

  const unsigned short* w_conv = wbf;
  const unsigned short* w_q    = wbf + 131072;
  const unsigned short* w_k    = wbf + 196608;
  const unsigned short* w_v    = wbf + 262144;
  const unsigned short* w_o    = wbf + 327680;
  const unsigned short* w_l1   = wbf + 393216;
  const unsigned short* w_l2   = wbf + 655360;

  float* out0 = (float*)d_out;
  float* out1f = out0 + (size_t)16 * 256 * 80 * 80;

  prep_kernel<<<5248, 256, 0, stream>>>(conv_w, q_w, k_w, v_w, out_w, lin1_w, lin2_w,
                                        wbf, pos, a4, a4tb);
  avgpool_kernel<<<dim3(40, 16), 640, 0, stream>>>(a3, pos, X3b);
  // conv + BN + pos -> X4
  fgemm<1><<<dim3(400, 1), 512, 0, stream>>>(a4tb, w_conv, conv_b, X4b, 512, 256, pos, bn_g, bn_b, nullptr);
  // fused Q/K/V (1200 blocks)
  qkv_kernel<<<dim3(400, 3), 512, 0, stream>>>(X3b, X4b, w_q, w_k, w_v,
      q_b, k_b, v_b, q_ln_g, q_ln_b, k_ln_g, k_ln_b, Qbb, Kbb, Vbb);
  // linear attention
  kv_kernel<<<640, 256, 0, stream>>>(Kbb, Vbb, KVp, Ksp);
  kvred_kernel<<<128, 256, 0, stream>>>(KVp, Ksp, KV, Ks);
  attn_kernel<<<3200, 256, 0, stream>>>(Qbb, KV, Ks, Kbb /*attn*/);
  // out1 = (X3-pos) + LN1(attn @ ow + ob)   -> o1b (bf16)
  fgemm<3><<<dim3(400, 1), 512, 0, stream>>>(Kbb, w_o, out_b, o1b, 256, 256, pos, n1_g, n1_b, X3b);
  // ffh = gelu(out1 @ l1w + l1b)
  fgemm<4><<<dim3(400, 4), 512, 0, stream>>>(o1b, w_l1, lin1_b, ffhb, 256, 1024, nullptr, nullptr, nullptr, nullptr);
  // out2 = out1 + LN2(ffh @ l2w + l2b), written as [b][c][40][40] bf16
  fgemm<5><<<dim3(400, 1), 512, 0, stream>>>(ffhb, w_l2, lin2_b, a3p, 1024, 256, nullptr, n2_g, n2_b, o1b);
  // fused upsample: out0 = up(a3p)*a3 ; out1 = up(a4)
  upsample_fused_kernel<<<12288, 256, 0, stream>>>(a3p, a3, a4, out0, out1f);
}